// Round 4
// baseline (183.248 us; speedup 1.0000x reference)
//
#include <hip/hip_runtime.h>

// retinex_synthesis, two-pass separable blur, transposed intermediate.
// out = clip(expm1(log1p(ins) + blur(log1p(bg) - log1p(ins))), 0, 1)
// blur folded to ONE separable 31-tap Gaussian of d = log1p(bg) - log1p(ins).
//
// R4 changes vs R3: 64x128 tiles (halo redundancy 1.47->1.23), 512-thread
// blocks, Phase-A loads batched into registers (one latency exposure),
// ONE barrier per block (direct per-thread 16B stores replace the LDS
// transpose; every 128B line is fully covered within a block -> L2 merges).

constexpr int W_ = 512, H_ = 512, NIMG = 48;
constexpr int RS = 158;        // staged rows: 128 outputs + 30 halo
constexpr int PITCH = 68;      // LDS row pitch in floats; 17 slots, 17%8==1 (balanced)
constexpr int NITEMS = RS * 16;  // 2528 float4 staging items per block

__device__ constexpr float G[31] = {
    8.8805851e-04f, 1.5861066e-03f, 2.7217699e-03f, 4.4874399e-03f,
    7.1084368e-03f, 1.0818767e-02f, 1.5820117e-02f, 2.2226435e-02f,
    3.0002549e-02f, 3.8911209e-02f, 4.8486352e-02f, 5.8048702e-02f,
    6.6771901e-02f, 7.3794364e-02f, 7.8357552e-02f, 7.9940480e-02f,
    7.8357552e-02f, 7.3794364e-02f, 6.6771901e-02f, 5.8048702e-02f,
    4.8486352e-02f, 3.8911209e-02f, 3.0002549e-02f, 2.2226435e-02f,
    1.5820117e-02f, 1.0818767e-02f, 7.1084368e-03f, 4.4874399e-03f,
    2.7217699e-03f, 1.5861066e-03f, 8.8805851e-04f};

// K1: d = log1p(bg)-log1p(ins), vertical blur, write tmpT[img][x][y].
// Tile: 64 wide (lane) x 128 tall (8 waves x 16 rows).
__global__ __launch_bounds__(512, 6) void vpass(const float* __restrict__ bg,
                                                const float* __restrict__ ins,
                                                float* __restrict__ tmpT) {
  __shared__ __align__(16) float sb[RS * PITCH];   // 42,976 B -> 3 blocks/CU
  const int tid = threadIdx.x;
  const int lane = tid & 63, w = tid >> 6;         // w = 0..7
  const int x0 = blockIdx.x * 64, y0 = blockIdx.y * 128;
  const size_t base = (size_t)blockIdx.z * ((size_t)H_ * W_);

  // Phase A1: issue ALL staging loads (predicated), results in registers.
  float4 bv[5], nv[5];
#pragma unroll
  for (int it = 0; it < 5; ++it) {
    const int idx = tid + 512 * it;
    const int r = idx >> 4, c = idx & 15;
    const int y = y0 - 15 + r;
    const bool ok = (idx < NITEMS) && ((unsigned)y < (unsigned)H_);
    bv[it] = make_float4(0.f, 0.f, 0.f, 0.f);
    nv[it] = bv[it];
    if (ok) {
      const size_t a = base + (size_t)y * W_ + x0 + 4 * c;
      bv[it] = *(const float4*)(bg + a);
      nv[it] = *(const float4*)(ins + a);
    }
  }
  // Phase A2: transform + LDS store.
#pragma unroll
  for (int it = 0; it < 5; ++it) {
    const int idx = tid + 512 * it;
    if (idx < NITEMS) {
      const int r = idx >> 4, c = idx & 15;
      float4 v;
      v.x = __logf(1.f + bv[it].x) - __logf(1.f + nv[it].x);
      v.y = __logf(1.f + bv[it].y) - __logf(1.f + nv[it].y);
      v.z = __logf(1.f + bv[it].z) - __logf(1.f + nv[it].z);
      v.w = __logf(1.f + bv[it].w) - __logf(1.f + nv[it].w);
      *(float4*)(sb + r * PITCH + 4 * c) = v;      // slot%8=(r+c)%8: balanced
    }
  }
  __syncthreads();                                  // the ONLY barrier

  // Phase B: wave w -> output rows y0+16w+p (p=0..15), col x0+lane.
  float acc[16];
#pragma unroll
  for (int p = 0; p < 16; ++p) acc[p] = 0.f;
#pragma unroll
  for (int j = 0; j < 46; ++j) {
    const float v = sb[(16 * w + j) * PITCH + lane];   // stride-1: 2 lanes/bank
#pragma unroll
    for (int p = 0; p < 16; ++p) {
      const int c = j - p;
      if (c >= 0 && c < 31) acc[p] += G[c] * v;
    }
  }
  // Phase C: direct transposed store — 64 contiguous bytes per thread.
  {
    float* dst = tmpT + base + (size_t)(x0 + lane) * H_ + y0 + 16 * w;
#pragma unroll
    for (int q = 0; q < 4; ++q)
      *(float4*)(dst + 4 * q) =
          make_float4(acc[4 * q], acc[4 * q + 1], acc[4 * q + 2], acc[4 * q + 3]);
  }
}

// K2: horizontal blur of tmpT (slide along x = row dim of tmpT), epilogue,
// write out in natural layout. Tile: 128 x-cols (8 waves x 16) x 64 y (lane).
__global__ __launch_bounds__(512, 6) void hpass(const float* __restrict__ tmpT,
                                                const float* __restrict__ ins,
                                                float* __restrict__ out) {
  __shared__ __align__(16) float sb[RS * PITCH];
  const int tid = threadIdx.x;
  const int lane = tid & 63, w = tid >> 6;
  const int x0 = blockIdx.x * 128, y0 = blockIdx.y * 64;
  const size_t base = (size_t)blockIdx.z * ((size_t)H_ * W_);

  // Phase A: stage tmpT "rows" x0-15..x0+142, cols y0..y0+63 (batched loads).
  float4 tv[5];
#pragma unroll
  for (int it = 0; it < 5; ++it) {
    const int idx = tid + 512 * it;
    const int r = idx >> 4, c = idx & 15;
    const int x = x0 - 15 + r;
    tv[it] = make_float4(0.f, 0.f, 0.f, 0.f);
    if ((idx < NITEMS) && ((unsigned)x < (unsigned)W_))
      tv[it] = *(const float4*)(tmpT + base + (size_t)x * H_ + y0 + 4 * c);
  }
#pragma unroll
  for (int it = 0; it < 5; ++it) {
    const int idx = tid + 512 * it;
    if (idx < NITEMS) {
      const int r = idx >> 4, c = idx & 15;
      *(float4*)(sb + r * PITCH + 4 * c) = tv[it];
    }
  }
  __syncthreads();

  // Phase B: wave w -> output cols x0+16w+p, row y0+lane.
  float acc[16];
#pragma unroll
  for (int p = 0; p < 16; ++p) acc[p] = 0.f;
#pragma unroll
  for (int j = 0; j < 46; ++j) {
    const float v = sb[(16 * w + j) * PITCH + lane];
#pragma unroll
    for (int p = 0; p < 16; ++p) {
      const int c = j - p;
      if (c >= 0 && c < 31) acc[p] += G[c] * v;
    }
  }
  // Phase C: fused epilogue; 64 contiguous bytes per thread in out.
  {
    const size_t a0 = base + (size_t)(y0 + lane) * W_ + x0 + 16 * w;
#pragma unroll
    for (int q = 0; q < 4; ++q) {
      const float4 n = *(const float4*)(ins + a0 + 4 * q);
      float4 o;
      o.x = fminf(fmaxf(__expf(__logf(1.f + n.x) + acc[4 * q + 0]) - 1.f, 0.f), 1.f);
      o.y = fminf(fmaxf(__expf(__logf(1.f + n.y) + acc[4 * q + 1]) - 1.f, 0.f), 1.f);
      o.z = fminf(fmaxf(__expf(__logf(1.f + n.z) + acc[4 * q + 2]) - 1.f, 0.f), 1.f);
      o.w = fminf(fmaxf(__expf(__logf(1.f + n.w) + acc[4 * q + 3]) - 1.f, 0.f), 1.f);
      *(float4*)(out + a0 + 4 * q) = o;
    }
  }
}

extern "C" void kernel_launch(void* const* d_in, const int* in_sizes, int n_in,
                              void* d_out, int out_size, void* d_ws, size_t ws_size,
                              hipStream_t stream) {
  const float* bg  = (const float*)d_in[0];
  const float* ins = (const float*)d_in[1];
  float* out = (float*)d_out;

  const size_t need = (size_t)NIMG * H_ * W_ * sizeof(float);
  float* tmpT = (ws_size >= need) ? (float*)d_ws : (float*)d_in[0];

  vpass<<<dim3(8, 4, NIMG), dim3(512), 0, stream>>>(bg, ins, tmpT);
  hpass<<<dim3(4, 8, NIMG), dim3(512), 0, stream>>>(tmpT, ins, out);
}

// Round 5
// 161.870 us; speedup vs baseline: 1.1321x; 1.1321x over previous
//
#include <hip/hip_runtime.h>

// retinex_synthesis, SINGLE-kernel rolling separable blur.
// out = clip(expm1(log1p(ins) + blur(log1p(bg) - log1p(ins))), 0, 1)
// blur folded to ONE separable 31-tap Gaussian of d = log1p(bg) - log1p(ins).
//
// Structure (R5): column strips 64 wide x 256 tall, one block each
// (grid 8*2*48 = 768 = exactly 3 blocks/CU). K-loop over 9 chunks of 32 rows:
//   stage chunk k (rows [32k-15, 32k+17), 96 cols) from PREFETCHED registers
//   -> LDS; prefetch chunk k+1 (loads in flight across barriers);
//   barrier; h-blur -> 64-row LDS ring; barrier;
//   emit output rows [32(k-1), 32k) by v-blur from ring + fused epilogue.
// Ring retention window [32k-47, 32k+17) exactly covers emission needs
// [32k-47, 32k+14]; every overwrite/read pair is barrier-separated.
// No global tmp, no second pass: compulsory traffic ~156 MB in + 50 MB out.

constexpr int W_ = 512, H_ = 512, NIMG = 48;
constexpr int SPITCH = 100;  // staging pitch (floats): 96 cols + 4; 25 slots, 25%8==1
constexpr int RPITCH = 68;   // ring pitch (floats): 64 cols + 4; 17 slots, 17%8==1

__device__ constexpr float G[31] = {
    8.8805851e-04f, 1.5861066e-03f, 2.7217699e-03f, 4.4874399e-03f,
    7.1084368e-03f, 1.0818767e-02f, 1.5820117e-02f, 2.2226435e-02f,
    3.0002549e-02f, 3.8911209e-02f, 4.8486352e-02f, 5.8048702e-02f,
    6.6771901e-02f, 7.3794364e-02f, 7.8357552e-02f, 7.9940480e-02f,
    7.8357552e-02f, 7.3794364e-02f, 6.6771901e-02f, 5.8048702e-02f,
    4.8486352e-02f, 3.8911209e-02f, 3.0002549e-02f, 2.2226435e-02f,
    1.5820117e-02f, 1.0818767e-02f, 7.1084368e-03f, 4.4874399e-03f,
    2.7217699e-03f, 1.5861066e-03f, 8.8805851e-04f};

__global__ __launch_bounds__(256, 3) void retinex_roll(const float* __restrict__ bg,
                                                       const float* __restrict__ ins,
                                                       float* __restrict__ out) {
  __shared__ __align__(16) float sd[32 * SPITCH];  // 12,800 B: staged d chunk
  __shared__ __align__(16) float hr[64 * RPITCH];  // 17,408 B: h-blurred ring

  const int tid  = threadIdx.x;
  const int lane = tid & 63;
  const int x0 = blockIdx.x * 64;
  const int y0 = blockIdx.y * 256;
  const size_t base = (size_t)blockIdx.z * (size_t)(H_ * W_);

  // Staging geometry (k-invariant): 768 float4 items = 32 rows x 24 slots.
  int sr[3], sc[3], gx[3]; bool okx[3];
#pragma unroll
  for (int s = 0; s < 3; ++s) {
    const int item = tid + 256 * s;
    sr[s] = item / 24;
    sc[s] = item - 24 * sr[s];
    gx[s] = x0 - 16 + 4 * sc[s];          // float4-aligned; OOB is whole-float4
    okx[s] = (unsigned)gx[s] < (unsigned)W_;
  }
  const int hrow = tid >> 3;              // h-blur: staged row 0..31
  const int hcg  = tid & 7;               // h-blur: col group (8 cols each)
  const int eg   = tid >> 6;              // emit: row-group 0..3

  // Initial prefetch: chunk 0 = rows y0-15 .. y0+16.
  float4 pb[3], pn[3];
#pragma unroll
  for (int s = 0; s < 3; ++s) {
    const int gy = y0 - 15 + sr[s];
    pb[s] = make_float4(0.f, 0.f, 0.f, 0.f);
    pn[s] = pb[s];
    if (okx[s] && (unsigned)gy < (unsigned)H_) {
      const size_t a = base + (size_t)gy * W_ + gx[s];
      pb[s] = *(const float4*)(bg + a);
      pn[s] = *(const float4*)(ins + a);
    }
  }

#pragma unroll 1
  for (int k = 0; k < 9; ++k) {
    // ---- Stage chunk k from prefetched registers: d = log1p(bg)-log1p(ins).
#pragma unroll
    for (int s = 0; s < 3; ++s) {
      float4 v;
      v.x = __logf(1.f + pb[s].x) - __logf(1.f + pn[s].x);
      v.y = __logf(1.f + pb[s].y) - __logf(1.f + pn[s].y);
      v.z = __logf(1.f + pb[s].z) - __logf(1.f + pn[s].z);
      v.w = __logf(1.f + pb[s].w) - __logf(1.f + pn[s].w);
      *(float4*)(sd + sr[s] * SPITCH + 4 * sc[s]) = v;   // slot%8=(sr+sc)%8
    }
    // ---- Prefetch chunk k+1 (same registers; stays in flight past barriers).
    if (k < 8) {
#pragma unroll
      for (int s = 0; s < 3; ++s) {
        const int gy = y0 + 32 * (k + 1) - 15 + sr[s];
        float4 b0 = make_float4(0.f, 0.f, 0.f, 0.f), n0 = b0;
        if (okx[s] && (unsigned)gy < (unsigned)H_) {
          const size_t a = base + (size_t)gy * W_ + gx[s];
          b0 = *(const float4*)(bg + a);
          n0 = *(const float4*)(ins + a);
        }
        pb[s] = b0; pn[s] = n0;
      }
    }
    __syncthreads();   // A: sd ready; also orders prev emit's hr reads vs h-blur writes

    // ---- H-blur staged row `hrow`, output cols 8*hcg..8*hcg+7 -> ring.
    {
      float win[40];
      const float4* p4 = (const float4*)(sd + hrow * SPITCH) + 2 * hcg;
#pragma unroll
      for (int q = 0; q < 10; ++q) {       // slot%8=(hrow+2hcg+q)%8: balanced
        const float4 v = p4[q];
        win[4 * q + 0] = v.x; win[4 * q + 1] = v.y;
        win[4 * q + 2] = v.z; win[4 * q + 3] = v.w;
      }
      float o[8];
#pragma unroll
      for (int e = 0; e < 8; ++e) {
        float a = 0.f;
#pragma unroll
        for (int c = 0; c < 31; ++c) a += G[c] * win[e + 1 + c];
        o[e] = a;
      }
      const int slot = (32 * k - 15 + hrow + 128) & 63;  // logical row 32k-15+hrow
      float* dst = hr + slot * RPITCH + 8 * hcg;
      *(float4*)(dst)     = make_float4(o[0], o[1], o[2], o[3]);
      *(float4*)(dst + 4) = make_float4(o[4], o[5], o[6], o[7]);
    }
    __syncthreads();   // B: ring rows for this chunk ready

    // ---- Emit output rows [32(k-1), 32k): v-blur from ring + epilogue.
    if (k >= 1) {
      const int t0 = 32 * (k - 1) + 8 * eg;    // block-relative first output row
      float acc[8];
#pragma unroll
      for (int p = 0; p < 8; ++p) acc[p] = 0.f;
#pragma unroll
      for (int j = 0; j < 38; ++j) {
        const int lr = t0 - 15 + j;            // logical ring row
        const float v = hr[((lr + 128) & 63) * RPITCH + lane];  // lane-consecutive
#pragma unroll
        for (int p = 0; p < 8; ++p) {
          const int c = j - p;
          if (c >= 0 && c < 31) acc[p] += G[c] * v;
        }
      }
#pragma unroll
      for (int p = 0; p < 8; ++p) {
        const size_t a = base + (size_t)(y0 + t0 + p) * W_ + x0 + lane;
        const float il = __logf(1.f + ins[a]);   // L2/LLC-hot (staged ~1 chunk ago)
        float r = __expf(il + acc[p]) - 1.f;
        out[a] = fminf(fmaxf(r, 0.f), 1.f);
      }
    }
  }
}

extern "C" void kernel_launch(void* const* d_in, const int* in_sizes, int n_in,
                              void* d_out, int out_size, void* d_ws, size_t ws_size,
                              hipStream_t stream) {
  const float* bg  = (const float*)d_in[0];
  const float* ins = (const float*)d_in[1];
  float* out = (float*)d_out;
  retinex_roll<<<dim3(8, 2, NIMG), dim3(256), 0, stream>>>(bg, ins, out);
}